// Round 2
// baseline (1854.406 us; speedup 1.0000x reference)
//
#include <hip/hip_runtime.h>

// MultiHeadAttention: B=4, S=2048, D=512, H=8, Dh=64.  ALL float32 I/O.
// Outputs (flat, concatenated): x [B,S,D] then attention [B,H,S,S].
//
// Workspace layout (fp32), total ~64.5 MB:
//   q   : ROWS*DM   (16 MB)
//   k   : ROWS*DM   (16 MB)
//   v   : ROWS*DM   (16 MB)
//   ctx : ROWS*DM   (16 MB)
//   m   : B*H*S     (256 KB)  row-wise softmax max
//   l   : B*H*S     (256 KB)  row-wise softmax denom

#define BATCH 4
#define SEQ   2048
#define DM    512
#define NH    8
#define DH    64
#define ROWS  (BATCH*SEQ)

// ---------------------------------------------------------------------------
// GEMM: C[r][c] = sum_d X[r][d]*W[c][d] + bias[c]   (x @ W.T + b)
// X: [M,512], W: [512,512], bias: [512], C: [M,512]; fp32.
// 64x64 output tile per block, 256 threads, each thread 4x4, BK=32.
// ---------------------------------------------------------------------------
__global__ __launch_bounds__(256) void proj_kernel(
    const float* __restrict__ X, const float* __restrict__ W,
    const float* __restrict__ bias, float* __restrict__ C)
{
    __shared__ float Xs[64][33];   // +1 pad: conflict-free column reads
    __shared__ float Ws[64][33];
    const int tid = threadIdx.x;
    const int tx = tid & 15, ty = tid >> 4;
    const int row0 = blockIdx.y * 64;
    const int col0 = blockIdx.x * 64;
    const int lr = tid >> 2;        // 0..63
    const int lc = (tid & 3) * 8;   // 0,8,16,24

    float acc[4][4];
    #pragma unroll
    for (int i = 0; i < 4; ++i)
        #pragma unroll
        for (int j = 0; j < 4; ++j) acc[i][j] = 0.f;

    for (int k0 = 0; k0 < DM; k0 += 32) {
        float4 x0 = *reinterpret_cast<const float4*>(X + (size_t)(row0 + lr) * DM + k0 + lc);
        float4 x1 = *reinterpret_cast<const float4*>(X + (size_t)(row0 + lr) * DM + k0 + lc + 4);
        float4 w0 = *reinterpret_cast<const float4*>(W + (size_t)(col0 + lr) * DM + k0 + lc);
        float4 w1 = *reinterpret_cast<const float4*>(W + (size_t)(col0 + lr) * DM + k0 + lc + 4);
        Xs[lr][lc+0]=x0.x; Xs[lr][lc+1]=x0.y; Xs[lr][lc+2]=x0.z; Xs[lr][lc+3]=x0.w;
        Xs[lr][lc+4]=x1.x; Xs[lr][lc+5]=x1.y; Xs[lr][lc+6]=x1.z; Xs[lr][lc+7]=x1.w;
        Ws[lr][lc+0]=w0.x; Ws[lr][lc+1]=w0.y; Ws[lr][lc+2]=w0.z; Ws[lr][lc+3]=w0.w;
        Ws[lr][lc+4]=w1.x; Ws[lr][lc+5]=w1.y; Ws[lr][lc+6]=w1.z; Ws[lr][lc+7]=w1.w;
        __syncthreads();
        #pragma unroll 8
        for (int kk = 0; kk < 32; ++kk) {
            float a[4], b[4];
            #pragma unroll
            for (int i = 0; i < 4; ++i) a[i] = Xs[ty*4+i][kk];
            #pragma unroll
            for (int j = 0; j < 4; ++j) b[j] = Ws[tx*4+j][kk];
            #pragma unroll
            for (int i = 0; i < 4; ++i)
                #pragma unroll
                for (int j = 0; j < 4; ++j)
                    acc[i][j] = fmaf(a[i], b[j], acc[i][j]);
        }
        __syncthreads();
    }
    float bv[4];
    #pragma unroll
    for (int j = 0; j < 4; ++j) bv[j] = bias[col0 + tx*4 + j];
    #pragma unroll
    for (int i = 0; i < 4; ++i) {
        float4 o;
        o.x = acc[i][0] + bv[0]; o.y = acc[i][1] + bv[1];
        o.z = acc[i][2] + bv[2]; o.w = acc[i][3] + bv[3];
        *reinterpret_cast<float4*>(C + (size_t)(row0 + ty*4 + i) * DM + col0 + tx*4) = o;
    }
}

// ---------------------------------------------------------------------------
// Pass 1: per-row softmax max (m) and denom (l) over the causal prefix.
// Block = (rb, h, b): 64 query rows, loops over key tiles ct=0..rb.
// Branch-free online update with sentinel -1e30 (masked scores); bogus
// all-masked partials are flushed by exp(-1e30 - m_f) = 0 in the merge.
// ---------------------------------------------------------------------------
__global__ __launch_bounds__(256) void attn_ml_kernel(
    const float* __restrict__ q, const float* __restrict__ k,
    float* __restrict__ mrow, float* __restrict__ lrow)
{
    __shared__ float Qs[64][65];
    __shared__ float Ks[64][65];
    __shared__ float Ms[64][17];
    __shared__ float Ls[64][17];
    const int rb = blockIdx.x, h = blockIdx.y, b = blockIdx.z;
    const int tid = threadIdx.x;
    const int tx = tid & 15, ty = tid >> 4;
    const int row0 = rb * 64;
    const int lr = tid >> 2;        // 0..63
    const int lc = (tid & 3) * 16;  // 0,16,32,48
    const size_t base = ((size_t)b * SEQ) * DM + h * DH;

    #pragma unroll
    for (int j = 0; j < 4; ++j) {
        float4 vq = *reinterpret_cast<const float4*>(q + base + (size_t)(row0 + lr) * DM + lc + j*4);
        Qs[lr][lc+j*4+0]=vq.x; Qs[lr][lc+j*4+1]=vq.y; Qs[lr][lc+j*4+2]=vq.z; Qs[lr][lc+j*4+3]=vq.w;
    }

    float mt[4], lt[4];
    #pragma unroll
    for (int i = 0; i < 4; ++i) { mt[i] = -1e30f; lt[i] = 0.f; }

    for (int ct = 0; ct <= rb; ++ct) {
        __syncthreads();
        #pragma unroll
        for (int j = 0; j < 4; ++j) {
            float4 vk = *reinterpret_cast<const float4*>(k + base + (size_t)(ct*64 + lr) * DM + lc + j*4);
            Ks[lr][lc+j*4+0]=vk.x; Ks[lr][lc+j*4+1]=vk.y; Ks[lr][lc+j*4+2]=vk.z; Ks[lr][lc+j*4+3]=vk.w;
        }
        __syncthreads();
        float s[4][4];
        #pragma unroll
        for (int i = 0; i < 4; ++i)
            #pragma unroll
            for (int j = 0; j < 4; ++j) s[i][j] = 0.f;
        #pragma unroll 8
        for (int d = 0; d < DH; ++d) {
            float a[4], bb[4];
            #pragma unroll
            for (int i = 0; i < 4; ++i) a[i] = Qs[ty*4+i][d];
            #pragma unroll
            for (int j = 0; j < 4; ++j) bb[j] = Ks[tx*4+j][d];
            #pragma unroll
            for (int i = 0; i < 4; ++i)
                #pragma unroll
                for (int j = 0; j < 4; ++j)
                    s[i][j] = fmaf(a[i], bb[j], s[i][j]);
        }
        const bool diag = (ct == rb);
        #pragma unroll
        for (int i = 0; i < 4; ++i) {
            float sv[4];
            #pragma unroll
            for (int j = 0; j < 4; ++j) {
                float x = s[i][j] * 0.125f;
                if (diag && (tx*4 + j > ty*4 + i)) x = -1e30f;
                sv[j] = x;
            }
            float tm = fmaxf(fmaxf(sv[0], sv[1]), fmaxf(sv[2], sv[3]));
            float mnew = fmaxf(mt[i], tm);
            float add = 0.f;
            #pragma unroll
            for (int j = 0; j < 4; ++j) add += __expf(sv[j] - mnew);
            lt[i] = lt[i] * __expf(mt[i] - mnew) + add;
            mt[i] = mnew;
        }
    }
    #pragma unroll
    for (int i = 0; i < 4; ++i) { Ms[ty*4+i][tx] = mt[i]; Ls[ty*4+i][tx] = lt[i]; }
    __syncthreads();
    if (tid < 64) {
        float mf = -1e30f;
        #pragma unroll
        for (int t = 0; t < 16; ++t) mf = fmaxf(mf, Ms[tid][t]);
        float lf = 0.f;
        #pragma unroll
        for (int t = 0; t < 16; ++t) lf += Ls[tid][t] * __expf(Ms[tid][t] - mf);
        const size_t n = ((size_t)(b * NH + h)) * SEQ + row0 + tid;
        mrow[n] = mf;
        lrow[n] = lf;
    }
}

// ---------------------------------------------------------------------------
// Pass 2: recompute scores, p = exp(s-m)/l, write attention (fp32, zeros in
// the strict upper triangle), accumulate ctx = P @ V.
// P round-trips through the Ks LDS buffer (reused after a sync).
// ---------------------------------------------------------------------------
__global__ __launch_bounds__(256) void attn_av_kernel(
    const float* __restrict__ q, const float* __restrict__ k, const float* __restrict__ v,
    const float* __restrict__ mrow, const float* __restrict__ lrow,
    float* __restrict__ att, float* __restrict__ ctx)
{
    __shared__ float Qs[64][65];
    __shared__ float Ks[64][65];   // scores phase: K tile; then reused as P tile
    __shared__ float Vs[64][65];
    __shared__ float Mv[64];
    __shared__ float Lv[64];
    const int rb = blockIdx.x, h = blockIdx.y, b = blockIdx.z;
    const int tid = threadIdx.x;
    const int tx = tid & 15, ty = tid >> 4;
    const int row0 = rb * 64;
    const int lr = tid >> 2;        // 0..63
    const int lc = (tid & 3) * 16;  // 0,16,32,48
    const size_t base = ((size_t)b * SEQ) * DM + h * DH;
    const size_t attbase = ((size_t)(b * NH + h)) * SEQ * SEQ;

    #pragma unroll
    for (int j = 0; j < 4; ++j) {
        float4 vq = *reinterpret_cast<const float4*>(q + base + (size_t)(row0 + lr) * DM + lc + j*4);
        Qs[lr][lc+j*4+0]=vq.x; Qs[lr][lc+j*4+1]=vq.y; Qs[lr][lc+j*4+2]=vq.z; Qs[lr][lc+j*4+3]=vq.w;
    }
    if (tid < 64) {
        const size_t n = ((size_t)(b * NH + h)) * SEQ + row0 + tid;
        Mv[tid] = mrow[n];
        Lv[tid] = 1.0f / lrow[n];
    }

    float oc[4][4];
    #pragma unroll
    for (int i = 0; i < 4; ++i)
        #pragma unroll
        for (int j = 0; j < 4; ++j) oc[i][j] = 0.f;

    for (int ct = 0; ct <= rb; ++ct) {
        __syncthreads();   // prev iter done reading Ks/Vs; Qs/Mv/Lv visible (1st iter)
        #pragma unroll
        for (int j = 0; j < 4; ++j) {
            float4 vk = *reinterpret_cast<const float4*>(k + base + (size_t)(ct*64 + lr) * DM + lc + j*4);
            float4 vv = *reinterpret_cast<const float4*>(v + base + (size_t)(ct*64 + lr) * DM + lc + j*4);
            Ks[lr][lc+j*4+0]=vk.x; Ks[lr][lc+j*4+1]=vk.y; Ks[lr][lc+j*4+2]=vk.z; Ks[lr][lc+j*4+3]=vk.w;
            Vs[lr][lc+j*4+0]=vv.x; Vs[lr][lc+j*4+1]=vv.y; Vs[lr][lc+j*4+2]=vv.z; Vs[lr][lc+j*4+3]=vv.w;
        }
        __syncthreads();
        float s[4][4];
        #pragma unroll
        for (int i = 0; i < 4; ++i)
            #pragma unroll
            for (int j = 0; j < 4; ++j) s[i][j] = 0.f;
        #pragma unroll 8
        for (int d = 0; d < DH; ++d) {
            float a[4], bb[4];
            #pragma unroll
            for (int i = 0; i < 4; ++i) a[i] = Qs[ty*4+i][d];
            #pragma unroll
            for (int j = 0; j < 4; ++j) bb[j] = Ks[tx*4+j][d];
            #pragma unroll
            for (int i = 0; i < 4; ++i)
                #pragma unroll
                for (int j = 0; j < 4; ++j)
                    s[i][j] = fmaf(a[i], bb[j], s[i][j]);
        }
        __syncthreads();   // everyone done reading Ks -> safe to reuse as P
        const bool diag = (ct == rb);
        #pragma unroll
        for (int i = 0; i < 4; ++i) {
            const float mi = Mv[ty*4+i];
            const float li = Lv[ty*4+i];
            float4 o;
            float p[4];
            #pragma unroll
            for (int j = 0; j < 4; ++j) {
                const bool valid = !diag || (tx*4 + j <= ty*4 + i);
                p[j] = valid ? __expf(s[i][j]*0.125f - mi) * li : 0.f;
                Ks[ty*4+i][tx*4+j] = p[j];
            }
            o.x = p[0]; o.y = p[1]; o.z = p[2]; o.w = p[3];
            *reinterpret_cast<float4*>(att + attbase + (size_t)(row0 + ty*4 + i) * SEQ + ct*64 + tx*4) = o;
        }
        __syncthreads();   // P visible
        #pragma unroll 8
        for (int cc = 0; cc < 64; ++cc) {
            float pv[4], vv[4];
            #pragma unroll
            for (int i = 0; i < 4; ++i) pv[i] = Ks[ty*4+i][cc];
            #pragma unroll
            for (int j = 0; j < 4; ++j) vv[j] = Vs[cc][tx*4+j];
            #pragma unroll
            for (int i = 0; i < 4; ++i)
                #pragma unroll
                for (int j = 0; j < 4; ++j)
                    oc[i][j] = fmaf(pv[i], vv[j], oc[i][j]);
        }
    }

    // zero the fully-masked tiles (cols >= (rb+1)*64)
    float4 z; z.x = 0.f; z.y = 0.f; z.z = 0.f; z.w = 0.f;
    for (int ct = rb + 1; ct < SEQ/64; ++ct) {
        #pragma unroll
        for (int i = 0; i < 4; ++i) {
            *reinterpret_cast<float4*>(att + attbase + (size_t)(row0 + ty*4 + i) * SEQ + ct*64 + tx*4) = z;
        }
    }

    // write ctx in [b, s, h*64+dv] layout (== transpose(0,2,1,3).reshape)
    #pragma unroll
    for (int i = 0; i < 4; ++i) {
        float4 o;
        o.x = oc[i][0]; o.y = oc[i][1]; o.z = oc[i][2]; o.w = oc[i][3];
        *reinterpret_cast<float4*>(ctx + ((size_t)b * SEQ + row0 + ty*4 + i) * DM + h*DH + tx*4) = o;
    }
}

// ---------------------------------------------------------------------------
extern "C" void kernel_launch(void* const* d_in, const int* in_sizes, int n_in,
                              void* d_out, int out_size, void* d_ws, size_t ws_size,
                              hipStream_t stream) {
    const float* Q   = (const float*)d_in[0];
    const float* K   = (const float*)d_in[1];
    const float* V   = (const float*)d_in[2];
    // d_in[3] = causal mask (ignored; deterministic)
    const float* w_q = (const float*)d_in[4];
    const float* b_q = (const float*)d_in[5];
    const float* w_k = (const float*)d_in[6];
    const float* b_k = (const float*)d_in[7];
    const float* w_v = (const float*)d_in[8];
    const float* b_v = (const float*)d_in[9];
    const float* w_o = (const float*)d_in[10];
    const float* b_o = (const float*)d_in[11];

    float* x_out   = (float*)d_out;                    // [B,S,D]
    float* att_out = x_out + (size_t)ROWS * DM;        // [B,H,S,S]

    float* qw = (float*)d_ws;
    float* kw = qw + (size_t)ROWS * DM;
    float* vw = kw + (size_t)ROWS * DM;
    float* cw = vw + (size_t)ROWS * DM;
    float* mr = cw + (size_t)ROWS * DM;
    float* lr = mr + (size_t)BATCH * NH * SEQ;

    dim3 pgrid(DM/64, ROWS/64);
    proj_kernel<<<pgrid, 256, 0, stream>>>(Q, w_q, b_q, qw);
    proj_kernel<<<pgrid, 256, 0, stream>>>(K, w_k, b_k, kw);
    proj_kernel<<<pgrid, 256, 0, stream>>>(V, w_v, b_v, vw);

    dim3 agrid(SEQ/64, NH, BATCH);
    attn_ml_kernel<<<agrid, 256, 0, stream>>>(qw, kw, mr, lr);
    attn_av_kernel<<<agrid, 256, 0, stream>>>(qw, kw, vw, mr, lr, att_out, cw);

    proj_kernel<<<pgrid, 256, 0, stream>>>(cw, w_o, b_o, x_out);
}

// Round 3
// 888.209 us; speedup vs baseline: 2.0878x; 2.0878x over previous
//
#include <hip/hip_runtime.h>

// MultiHeadAttention: B=4, S=2048, D=512, H=8, Dh=64.  fp32 I/O, bf16 MFMA core.
// Outputs (flat): x [B,S,D] fp32, attention [B,H,S,S] fp32.
//
// Workspace: q,k,v,ctx bf16 [ROWS*DM] (8 MB each), m,l fp32 [B*H*S].

#define BATCH 4
#define SEQ   2048
#define DM    512
#define NH    8
#define DH    64
#define ROWS  (BATCH*SEQ)
#define QT    (SEQ/64)

typedef unsigned short u16;
using bf8   = __attribute__((ext_vector_type(8))) short;   // 8 bf16 (4 VGPRs)
using f32x4 = __attribute__((ext_vector_type(4))) float;   // 4 fp32 acc

__device__ __forceinline__ float b2f(u16 u) {
    union { unsigned int i; float f; } v; v.i = ((unsigned int)u) << 16; return v.f;
}
__device__ __forceinline__ u16 f2b(float f) {
    union { float fl; unsigned int i; } v; v.fl = f;
    return (u16)((v.i + 0x7FFFu + ((v.i >> 16) & 1u)) >> 16);  // RNE
}

// ---------------------------------------------------------------------------
// MFMA GEMM: C[r][c] = sum_d X[r][d]*W[c][d] + bias[c]   (x @ W.T + b)
// 128x128 tile, BK=32, 256 threads = 4 waves (2x2), 16 MFMA tiles/wave.
// IN_BF16: X is bf16 (ctx ws) else fp32 (converted during staging).
// OUT_BF16: C bf16 (q/k/v ws) else fp32 (x_out). W/bias always fp32.
// ---------------------------------------------------------------------------
template<bool IN_BF16, bool OUT_BF16>
__global__ __launch_bounds__(256) void proj_mfma(
    const void* __restrict__ Xv, const float* __restrict__ W,
    const float* __restrict__ bias, void* __restrict__ Cv)
{
    __shared__ u16 Xs[128][40];   // +8 bf16 pad: keeps rows 16B-aligned, 2-way max
    __shared__ u16 Wsh[128][40];
    const int tid  = threadIdx.x;
    const int lane = tid & 63;
    const int w    = tid >> 6;
    const int wm = (w >> 1) * 64, wn = (w & 1) * 64;
    const int lc = lane & 15, lq = lane >> 4;
    const int row0 = blockIdx.y * 128;
    const int col0 = blockIdx.x * 128;

    const f32x4 fzero = {0.f, 0.f, 0.f, 0.f};
    f32x4 acc[4][4];
    #pragma unroll
    for (int mt = 0; mt < 4; ++mt)
        #pragma unroll
        for (int nt = 0; nt < 4; ++nt) acc[mt][nt] = fzero;

    for (int k0 = 0; k0 < DM; k0 += 32) {
        __syncthreads();
        if (IN_BF16) {
            const u16* Xg = (const u16*)Xv;
            const int r = tid >> 2, kc = (tid & 3) * 8;
            #pragma unroll
            for (int rr = 0; rr < 2; ++rr)
                *(bf8*)&Xs[r + rr*64][kc] =
                    *(const bf8*)(Xg + (size_t)(row0 + r + rr*64) * DM + k0 + kc);
        } else {
            const float* Xg = (const float*)Xv;
            const int r = tid >> 3, kc = (tid & 7) * 4;
            #pragma unroll
            for (int rr = 0; rr < 4; ++rr) {
                float4 vx = *(const float4*)(Xg + (size_t)(row0 + r + rr*32) * DM + k0 + kc);
                u16 t4[4] = { f2b(vx.x), f2b(vx.y), f2b(vx.z), f2b(vx.w) };
                *(uint2*)&Xs[r + rr*32][kc] = *(uint2*)t4;
            }
        }
        {
            const int r = tid >> 3, kc = (tid & 7) * 4;
            #pragma unroll
            for (int rr = 0; rr < 4; ++rr) {
                float4 vw = *(const float4*)(W + (size_t)(col0 + r + rr*32) * DM + k0 + kc);
                u16 t4[4] = { f2b(vw.x), f2b(vw.y), f2b(vw.z), f2b(vw.w) };
                *(uint2*)&Wsh[r + rr*32][kc] = *(uint2*)t4;
            }
        }
        __syncthreads();
        bf8 a[4], b[4];
        #pragma unroll
        for (int mt = 0; mt < 4; ++mt) a[mt] = *(const bf8*)&Xs[wm + mt*16 + lc][lq*8];
        #pragma unroll
        for (int nt = 0; nt < 4; ++nt) b[nt] = *(const bf8*)&Wsh[wn + nt*16 + lc][lq*8];
        #pragma unroll
        for (int mt = 0; mt < 4; ++mt)
            #pragma unroll
            for (int nt = 0; nt < 4; ++nt)
                acc[mt][nt] = __builtin_amdgcn_mfma_f32_16x16x32_bf16(a[mt], b[nt], acc[mt][nt], 0, 0, 0);
    }
    // epilogue: D row=(lane>>4)*4+reg, col=lane&15 (m89-verified layout)
    #pragma unroll
    for (int nt = 0; nt < 4; ++nt) {
        const int col = col0 + wn + nt*16 + lc;
        const float bv = bias[col];
        #pragma unroll
        for (int mt = 0; mt < 4; ++mt) {
            #pragma unroll
            for (int r = 0; r < 4; ++r) {
                const int row = row0 + wm + mt*16 + lq*4 + r;
                const float val = acc[mt][nt][r] + bv;
                if (OUT_BF16) ((u16*)Cv)[(size_t)row * DM + col] = f2b(val);
                else          ((float*)Cv)[(size_t)row * DM + col] = val;
            }
        }
    }
}

// ---------------------------------------------------------------------------
// Pass 1: row-wise softmax max m and denom l over the causal prefix, MFMA QK^T.
// Block = (pair, h, b): processes qt = pair and qt = 31-pair sequentially
// (uniform 33 tile-iters/block). Per-lane online (m,l) partials over its
// column subset; -1e30 sentinel partials flushed at the LDS merge.
// ---------------------------------------------------------------------------
__global__ __launch_bounds__(256) void attn_ml(
    const u16* __restrict__ q, const u16* __restrict__ k,
    float* __restrict__ mrow, float* __restrict__ lrow)
{
    __shared__ u16 Qs[64][72];
    __shared__ u16 Ks[64][72];
    __shared__ float Ms[64][17];
    __shared__ float Ls[64][17];
    const int tid = threadIdx.x, lane = tid & 63, w = tid >> 6;
    const int lc = lane & 15, lq = lane >> 4;
    const int h = blockIdx.y, b = blockIdx.z;
    const size_t base = ((size_t)b * SEQ) * DM + h * DH;
    const int sr = tid >> 3, sc = (tid & 7) * 8;
    const f32x4 fzero = {0.f, 0.f, 0.f, 0.f};

    for (int qi = 0; qi < 2; ++qi) {
        const int qt = qi ? (QT - 1 - (int)blockIdx.x) : (int)blockIdx.x;
        __syncthreads();
        #pragma unroll
        for (int rr = 0; rr < 2; ++rr)
            *(bf8*)&Qs[sr + rr*32][sc] =
                *(const bf8*)(q + base + (size_t)(qt*64 + sr + rr*32) * DM + sc);

        float m_p[4], l_p[4];
        #pragma unroll
        for (int r = 0; r < 4; ++r) { m_p[r] = -1e30f; l_p[r] = 0.f; }

        for (int kt = 0; kt <= qt; ++kt) {
            __syncthreads();
            #pragma unroll
            for (int rr = 0; rr < 2; ++rr)
                *(bf8*)&Ks[sr + rr*32][sc] =
                    *(const bf8*)(k + base + (size_t)(kt*64 + sr + rr*32) * DM + sc);
            __syncthreads();
            f32x4 s[4];
            #pragma unroll
            for (int nt = 0; nt < 4; ++nt) s[nt] = fzero;
            #pragma unroll
            for (int ks = 0; ks < 2; ++ks) {
                bf8 a = *(const bf8*)&Qs[w*16 + lc][ks*32 + lq*8];
                #pragma unroll
                for (int nt = 0; nt < 4; ++nt) {
                    bf8 bb = *(const bf8*)&Ks[nt*16 + lc][ks*32 + lq*8];
                    s[nt] = __builtin_amdgcn_mfma_f32_16x16x32_bf16(a, bb, s[nt], 0, 0, 0);
                }
            }
            const bool diag = (kt == qt);
            #pragma unroll
            for (int r = 0; r < 4; ++r) {
                const int rowl = w*16 + lq*4 + r;
                float sv[4];
                #pragma unroll
                for (int nt = 0; nt < 4; ++nt) {
                    float x = s[nt][r] * 0.125f;
                    if (diag && (nt*16 + lc > rowl)) x = -1e30f;
                    sv[nt] = x;
                }
                const float tm = fmaxf(fmaxf(sv[0], sv[1]), fmaxf(sv[2], sv[3]));
                const float mnew = fmaxf(m_p[r], tm);
                float add = __expf(sv[0]-mnew) + __expf(sv[1]-mnew)
                          + __expf(sv[2]-mnew) + __expf(sv[3]-mnew);
                l_p[r] = l_p[r] * __expf(m_p[r] - mnew) + add;
                m_p[r] = mnew;
            }
        }
        #pragma unroll
        for (int r = 0; r < 4; ++r) {
            Ms[w*16 + lq*4 + r][lc] = m_p[r];
            Ls[w*16 + lq*4 + r][lc] = l_p[r];
        }
        __syncthreads();
        if (tid < 64) {
            float mf = -1e30f;
            #pragma unroll
            for (int t = 0; t < 16; ++t) mf = fmaxf(mf, Ms[tid][t]);
            float lf = 0.f;
            #pragma unroll
            for (int t = 0; t < 16; ++t) lf += Ls[tid][t] * __expf(Ms[tid][t] - mf);
            const size_t n = ((size_t)(b * NH + h)) * SEQ + qt*64 + tid;
            mrow[n] = mf;
            lrow[n] = lf;
        }
    }
}

// ---------------------------------------------------------------------------
// Pass 2: p = exp(s-m)/l via MFMA QK^T; write att fp32; ctx += P@V via MFMA.
// P round-trips through LDS bf16 (C-layout out, A-layout in, intra-wave rows).
// V staged transposed (Vt[dv][j]) for the B operand.
// ---------------------------------------------------------------------------
__global__ __launch_bounds__(256) void attn_av(
    const u16* __restrict__ q, const u16* __restrict__ k, const u16* __restrict__ v,
    const float* __restrict__ mrow, const float* __restrict__ lrow,
    float* __restrict__ att, u16* __restrict__ ctx)
{
    __shared__ u16 Qs[64][72];
    __shared__ u16 Ks[64][72];
    __shared__ u16 Vt[64][72];
    __shared__ u16 Ps[64][72];
    __shared__ float Mv[64];
    __shared__ float Lv[64];
    const int tid = threadIdx.x, lane = tid & 63, w = tid >> 6;
    const int lc = lane & 15, lq = lane >> 4;
    const int h = blockIdx.y, b = blockIdx.z;
    const size_t base = ((size_t)b * SEQ) * DM + h * DH;
    const size_t attbase = ((size_t)(b * NH + h)) * SEQ * SEQ;
    const int sr = tid >> 3, sc = (tid & 7) * 8;
    const f32x4 fzero = {0.f, 0.f, 0.f, 0.f};

    for (int qi = 0; qi < 2; ++qi) {
        const int qt = qi ? (QT - 1 - (int)blockIdx.x) : (int)blockIdx.x;
        __syncthreads();
        #pragma unroll
        for (int rr = 0; rr < 2; ++rr)
            *(bf8*)&Qs[sr + rr*32][sc] =
                *(const bf8*)(q + base + (size_t)(qt*64 + sr + rr*32) * DM + sc);
        if (tid < 64) {
            const size_t n = ((size_t)(b * NH + h)) * SEQ + qt*64 + tid;
            Mv[tid] = mrow[n];
            Lv[tid] = 1.0f / lrow[n];
        }
        f32x4 oc[4];
        #pragma unroll
        for (int nt = 0; nt < 4; ++nt) oc[nt] = fzero;

        for (int kt = 0; kt <= qt; ++kt) {
            __syncthreads();   // prev iter's MFMA reads done; Qs/Mv visible (1st)
            #pragma unroll
            for (int rr = 0; rr < 2; ++rr)
                *(bf8*)&Ks[sr + rr*32][sc] =
                    *(const bf8*)(k + base + (size_t)(kt*64 + sr + rr*32) * DM + sc);
            {   // V transposed: Vt[dv][j] = V[kt*64+j][h*64+dv]
                const int dv = tid & 63, jg = (tid >> 6) * 16;
                u16 tv[16];
                #pragma unroll
                for (int i = 0; i < 16; ++i)
                    tv[i] = v[base + (size_t)(kt*64 + jg + i) * DM + dv];
                *(bf8*)&Vt[dv][jg]     = *(bf8*)&tv[0];
                *(bf8*)&Vt[dv][jg + 8] = *(bf8*)&tv[8];
            }
            __syncthreads();
            f32x4 s[4];
            #pragma unroll
            for (int nt = 0; nt < 4; ++nt) s[nt] = fzero;
            #pragma unroll
            for (int ks = 0; ks < 2; ++ks) {
                bf8 a = *(const bf8*)&Qs[w*16 + lc][ks*32 + lq*8];
                #pragma unroll
                for (int nt = 0; nt < 4; ++nt) {
                    bf8 bb = *(const bf8*)&Ks[nt*16 + lc][ks*32 + lq*8];
                    s[nt] = __builtin_amdgcn_mfma_f32_16x16x32_bf16(a, bb, s[nt], 0, 0, 0);
                }
            }
            const bool diag = (kt == qt);
            #pragma unroll
            for (int nt = 0; nt < 4; ++nt) {
                #pragma unroll
                for (int r = 0; r < 4; ++r) {
                    const int rowl = w*16 + lq*4 + r;
                    const int coll = nt*16 + lc;
                    float p = 0.f;
                    if (!diag || coll <= rowl)
                        p = __expf(s[nt][r] * 0.125f - Mv[rowl]) * Lv[rowl];
                    att[attbase + (size_t)(qt*64 + rowl) * SEQ + kt*64 + coll] = p;
                    Ps[rowl][coll] = f2b(p);
                }
            }
            __syncthreads();   // Ps visible (safety; rows are intra-wave)
            #pragma unroll
            for (int ks = 0; ks < 2; ++ks) {
                bf8 a = *(const bf8*)&Ps[w*16 + lc][ks*32 + lq*8];
                #pragma unroll
                for (int nt = 0; nt < 4; ++nt) {
                    bf8 bb = *(const bf8*)&Vt[nt*16 + lc][ks*32 + lq*8];
                    oc[nt] = __builtin_amdgcn_mfma_f32_16x16x32_bf16(a, bb, oc[nt], 0, 0, 0);
                }
            }
        }
        // ctx (bf16) in [b, s, h*64+dv] layout
        #pragma unroll
        for (int nt = 0; nt < 4; ++nt) {
            #pragma unroll
            for (int r = 0; r < 4; ++r) {
                const int rowl = w*16 + lq*4 + r;
                ctx[((size_t)b * SEQ + qt*64 + rowl) * DM + h*DH + nt*16 + lc] = f2b(oc[nt][r]);
            }
        }
        // zero fully-masked tiles (cols >= (qt+1)*64)
        {
            const int zr = tid >> 2, zc0 = (tid & 3) * 16;
            const float4 z = {0.f, 0.f, 0.f, 0.f};
            for (int ct = qt + 1; ct < QT; ++ct) {
                #pragma unroll
                for (int jj = 0; jj < 4; ++jj)
                    *(float4*)(att + attbase + (size_t)(qt*64 + zr) * SEQ + ct*64 + zc0 + jj*4) = z;
            }
        }
    }
}

// ---------------------------------------------------------------------------
extern "C" void kernel_launch(void* const* d_in, const int* in_sizes, int n_in,
                              void* d_out, int out_size, void* d_ws, size_t ws_size,
                              hipStream_t stream) {
    const float* Q   = (const float*)d_in[0];
    const float* K   = (const float*)d_in[1];
    const float* V   = (const float*)d_in[2];
    // d_in[3] = causal mask (ignored; deterministic)
    const float* w_q = (const float*)d_in[4];
    const float* b_q = (const float*)d_in[5];
    const float* w_k = (const float*)d_in[6];
    const float* b_k = (const float*)d_in[7];
    const float* w_v = (const float*)d_in[8];
    const float* b_v = (const float*)d_in[9];
    const float* w_o = (const float*)d_in[10];
    const float* b_o = (const float*)d_in[11];

    float* x_out   = (float*)d_out;                    // [B,S,D]
    float* att_out = x_out + (size_t)ROWS * DM;        // [B,H,S,S]

    u16* qw = (u16*)d_ws;
    u16* kw = qw + (size_t)ROWS * DM;
    u16* vw = kw + (size_t)ROWS * DM;
    u16* cw = vw + (size_t)ROWS * DM;
    float* mr = (float*)(cw + (size_t)ROWS * DM);
    float* lr = mr + (size_t)BATCH * NH * SEQ;

    dim3 pgrid(DM/128, ROWS/128);   // (4, 64)
    proj_mfma<false, true><<<pgrid, 256, 0, stream>>>(Q, w_q, b_q, qw);
    proj_mfma<false, true><<<pgrid, 256, 0, stream>>>(K, w_k, b_k, kw);
    proj_mfma<false, true><<<pgrid, 256, 0, stream>>>(V, w_v, b_v, vw);

    dim3 agrid(QT/2, NH, BATCH);    // (16, 8, 4) — balanced qt pairs
    attn_ml<<<agrid, 256, 0, stream>>>(qw, kw, mr, lr);
    attn_av<<<agrid, 256, 0, stream>>>(qw, kw, vw, mr, lr, att_out, cw);

    proj_mfma<true, false><<<pgrid, 256, 0, stream>>>(cw, w_o, b_o, x_out);
}